// Round 14
// baseline (145.430 us; speedup 1.0000x reference)
//
#include <hip/hip_runtime.h>

#define HH 512
#define WW 512
#define NCH 3
#define NBATCH 16
#define NIMG (NBATCH*NCH)     // 48
#define CHUNK 16              // output rows per wave
#define NCHUNK (HH/CHUNK)     // 32
#define NSTRIP 4              // 128-col strips
#define SW 128
#define SLOTS 142             // pad=6: col c <-> slot c-c0+6, slots 0..141
#define NWAVE 4               // waves per block (independent units, no barriers)
#define NT (64*NWAVE)         // 256 threads
#define NUNITS (NIMG*NCHUNK*NSTRIP)      // 6144 wave-units
#define BLKS_PER_B (NCH*NCHUNK*NSTRIP)   // 384 partial slots per batch elem

struct RowData { float4 m; float2 h; };

// R22 = R21 + 6-DEEP BOTH STREAMS + DEAD-LOAD-FREE TAIL.
//  Model (validated quantitatively on R21 counters): kernel is MLP-bound —
//  achieved 4.0 B/cyc/CU ~= (outstanding-bytes / latency) = 21 loads/SIMD x
//  16B / ~600cyc = 4.5. All timing-only tweaks (R10/R13/R21-lead) were
//  neutral because they didn't change the outstanding-load count; R18 won
//  because counted vmcnt let loads stay in flight. So: RAISE the in-flight
//  count. 12 RowData named registers = 6-deep new stream + 6-deep old stream
//  (~16 outstanding loads/wave, 2x R21). Refill: new it+6, old it-5 (each
//  consumed 6 bodies later = row (it+6)-11 — same post-slide-shift schedule
//  R21 verified). Loop split 10..19 (refill) / 20..25 (pure consume: all
//  rows already in registers) removes R21's 6 dead clamped loads per unit
//  (-14% fetch) while keeping per-loop VMEM counts constant (R18 lesson).
//  Carried: R18 branchless clamped+masked loads; R17 4-wave packing;
//  R15/R16 ring-free vertical slide + slide-only warmup.
__global__ __launch_bounds__(NT) void ssim_main(
    const float* __restrict__ pred, const float* __restrict__ targ,
    float* __restrict__ ws)
{
  // per-wave vertical-sum staging slices (same-wave in-order LDS; no barriers
  // — validated R2-R21). Row stride 142*8B = 16B multiple -> rows 16B-aligned.
  __shared__ __align__(16) float2 arrA[NWAVE][SLOTS];   // (Sx, Sy) per col
  __shared__ __align__(16) float2 arrB[NWAVE][SLOTS];   // (Sxy, Sss) per col

  const int tid = threadIdx.x;
  const int wid = tid >> 6;              // wave id 0..3
  const int l   = tid & 63;              // lane id
  const int unit = blockIdx.x * NWAVE + wid;   // == old single-wave blk id
  const int img = unit >> 7;             // / (NCHUNK*NSTRIP) = /128
  const int rem = unit & 127;
  const int chunk = rem >> 2;
  const int strip = rem & 3;

  const int r0 = chunk*CHUNK - 5;        // first input row
  const int c0 = strip*SW;

  const size_t ib = (size_t)img * (size_t)(HH*WW);
  const float* pp = pred + ib;
  const float* tp = targ + ib;

  const int cm = c0 + 2*l;               // this lane's 2 main cols
  const int h  = l - 54;                 // halo id 0..9 on lanes 54..63
  const int ch = (h < 5) ? (c0 - 5 + h) : (c0 + 123 + h);   // halo col
  const bool hval = (l >= 54) && ((unsigned)ch < (unsigned)WW);
  const int chc = min(max(ch, 0), WW-1); // clamped halo col (always loadable)
  const int hs = (h < 5) ? (1 + h) : (129 + h);  // halo slot (pad=6)

  float2* const wA = arrA[wid];
  float2* const wB = arrB[wid];

  // BRANCHLESS row load: constant instruction stream (2x b64 + 2x b32 every
  // call), clamped addresses, 0/1 mask preserves zero-padding semantics.
  auto loadrow_nb = [&](int it) -> RowData {
    const int r = r0 + it;
    const int rc = min(max(r, 0), HH-1);
    const float mask = ((unsigned)r < (unsigned)HH) ? 1.f : 0.f;
    const float hm = hval ? mask : 0.f;
    const size_t ro = (size_t)rc * WW;
    const float2 x = *(const float2*)(pp + ro + cm);
    const float2 y = *(const float2*)(tp + ro + cm);
    const float hx = pp[ro + chc], hy = tp[ro + chc];
    RowData d;
    d.m = make_float4(x.x*mask, x.y*mask, y.x*mask, y.y*mask);
    d.h = make_float2(hx*hm, hy*hm);
    return d;
  };

  // vertical running sums over the 11-row window — all registers, no history
  float vx0=0.f, vy0=0.f, vxy0=0.f, vss0=0.f;    // main col 0 (cm)
  float vx1=0.f, vy1=0.f, vxy1=0.f, vss1=0.f;    // main col 1 (cm+1)
  float vxh=0.f, vyh=0.f, vxyh=0.f, vssh=0.f;    // halo col (lanes 54..63)
  float acc = 0.f;

  const RowData zrow = { make_float4(0.f,0.f,0.f,0.f), make_float2(0.f,0.f) };

  // new-row stream: 6-deep, rows it..it+5 in registers
  RowData curN = loadrow_nb(0);
  RowData nxtN = loadrow_nb(1);
  RowData nx2N = loadrow_nb(2);
  RowData nx3N = loadrow_nb(3);
  RowData nx4N = loadrow_nb(4);
  RowData nx5N = loadrow_nb(5);

  constexpr float c1 = 0.0001f, c2 = 0.0009f, inv121 = 1.0f/121.0f;

  auto ssim1 = [&](float Sx, float Sy, float Sxy, float Sss) -> float {
    const float mux = Sx*inv121, muy = Sy*inv121;
    const float muxy = mux*muy;
    const float m2   = fmaf(mux, mux, muy*muy);
    const float sgxy = fmaf(Sxy, inv121, -muxy);
    const float sgss = fmaf(Sss, inv121, -m2);
    const float num = fmaf(2.f, muxy, c1) * fmaf(2.f, sgxy, c2);
    const float den = (m2 + c1) * (sgss + c2);
    const float s = num * __builtin_amdgcn_rcpf(den);
    return fminf(fmaxf(s, 0.f), 1.f);
  };

  // shared slide step (pure VALU)
  auto slide = [&](const RowData& nw, const RowData& od) {
    const float xn0 = nw.m.x, xn1 = nw.m.y;
    const float yn0 = nw.m.z, yn1 = nw.m.w;
    const float xo0 = od.m.x, xo1 = od.m.y;
    const float yo0 = od.m.z, yo1 = od.m.w;
    vx0  += xn0 - xo0;  vy0  += yn0 - yo0;
    vx1  += xn1 - xo1;  vy1  += yn1 - yo1;
    vxy0 += xn0*yn0 - xo0*yo0;
    vxy1 += xn1*yn1 - xo1*yo1;
    vss0 += fmaf(xn0, xn0, yn0*yn0) - fmaf(xo0, xo0, yo0*yo0);
    vss1 += fmaf(xn1, xn1, yn1*yn1) - fmaf(xo1, xo1, yo1*yo1);
    const float xnh = nw.h.x, ynh = nw.h.y;
    const float xoh = od.h.x, yoh = od.h.y;
    vxh  += xnh - xoh;  vyh  += ynh - yoh;
    vxyh += xnh*ynh - xoh*yoh;
    vssh += fmaf(xnh, xnh, ynh*ynh) - fmaf(xoh, xoh, yoh*yoh);
  };

  auto shiftN = [&]() {
    curN = nxtN; nxtN = nx2N; nx2N = nx3N; nx3N = nx4N; nx4N = nx5N;
  };

  // emit-path tail of a steady body: stage + taps + ssim (identical R15-R21)
  auto emit = [&]() {
    *(float4*)(wA + 6 + 2*l) = make_float4(vx0, vy0, vx1, vy1);
    *(float4*)(wB + 6 + 2*l) = make_float4(vxy0, vss0, vxy1, vss1);
    if (l >= 54) {
      wA[hs] = make_float2(vxh, vyh);
      wB[hs] = make_float2(vxyh, vssh);
    }

    const float4* ta = (const float4*)(wA) + l;
    const float4 a0v = ta[0], a1v = ta[1], a2v = ta[2], a3v = ta[3],
                 a4v = ta[4], a5v = ta[5], a6v = ta[6];
    const float4* tb = (const float4*)(wB) + l;
    const float4 b0v = tb[0], b1v = tb[1], b2v = tb[2], b3v = tb[3],
                 b4v = tb[4], b5v = tb[5], b6v = tb[6];

    float Sx = a0v.z, Sy = a0v.w;
    Sx += a1v.x; Sy += a1v.y;  Sx += a1v.z; Sy += a1v.w;
    Sx += a2v.x; Sy += a2v.y;  Sx += a2v.z; Sy += a2v.w;
    Sx += a3v.x; Sy += a3v.y;  Sx += a3v.z; Sy += a3v.w;
    Sx += a4v.x; Sy += a4v.y;  Sx += a4v.z; Sy += a4v.w;
    Sx += a5v.x; Sy += a5v.y;  Sx += a5v.z; Sy += a5v.w;
    const float Sx1 = Sx - a0v.z + a6v.x;
    const float Sy1 = Sy - a0v.w + a6v.y;

    float Sxy = b0v.z, Sss = b0v.w;
    Sxy += b1v.x; Sss += b1v.y;  Sxy += b1v.z; Sss += b1v.w;
    Sxy += b2v.x; Sss += b2v.y;  Sxy += b2v.z; Sss += b2v.w;
    Sxy += b3v.x; Sss += b3v.y;  Sxy += b3v.z; Sss += b3v.w;
    Sxy += b4v.x; Sss += b4v.y;  Sxy += b4v.z; Sss += b4v.w;
    Sxy += b5v.x; Sss += b5v.y;  Sxy += b5v.z; Sss += b5v.w;
    const float Sxy1 = Sxy - b0v.z + b6v.x;
    const float Sss1 = Sss - b0v.w + b6v.y;

    acc += ssim1(Sx,  Sy,  Sxy,  Sss);
    acc += ssim1(Sx1, Sy1, Sxy1, Sss1);
  };

  // warmup bodies 0..4: slide-only; old row structurally ZERO (no load)
  #pragma clang loop unroll_count(2)
  for (int it = 0; it < 5; ++it) {
    slide(curN, zrow);
    shiftN(); nx5N = loadrow_nb(it + 6);
  }
  // warmup bodies 5..9: start the old stream (rows 0..4). Entering body 10:
  // o0=zrow (body 10 subtracts nothing — R20 lesson), o1..o5 = rows 0..4.
  RowData o0, o1, o2, o3, o4, o5;
  slide(curN, zrow); shiftN(); nx5N = loadrow_nb(11); o1 = loadrow_nb(0);
  slide(curN, zrow); shiftN(); nx5N = loadrow_nb(12); o2 = loadrow_nb(1);
  slide(curN, zrow); shiftN(); nx5N = loadrow_nb(13); o3 = loadrow_nb(2);
  slide(curN, zrow); shiftN(); nx5N = loadrow_nb(14); o4 = loadrow_nb(3);
  slide(curN, zrow); shiftN(); nx5N = loadrow_nb(15); o5 = loadrow_nb(4);
  o0 = zrow;

  // steady bodies 10..19: refill both streams. Refill loaded at body it is
  // consumed 6 bodies later: new = row it+6, old = row it-5 = (it+6)-11.
  #pragma clang loop unroll_count(2)
  for (int it = 10; it < 20; ++it) {
    slide(curN, o0);
    shiftN(); nx5N = loadrow_nb(it + 6);
    o0 = o1; o1 = o2; o2 = o3; o3 = o4; o4 = o5;
    o5 = loadrow_nb(it - 5);
    emit();
  }

  // tail bodies 20..25: pure consume — every needed row (new 20..25, old
  // 9..14) is already in registers. Zero dead loads (R21 had 6/unit).
  #pragma clang loop unroll_count(2)
  for (int it = 20; it < 26; ++it) {
    slide(curN, o0);
    shiftN();
    o0 = o1; o1 = o2; o2 = o3; o3 = o4; o4 = o5;
    emit();
  }

  // per-wave reduction -> per-unit partial slot (written unconditionally: no
  // memset of d_ws needed, no atomics; waves are fully independent)
  #pragma unroll
  for (int off = 32; off > 0; off >>= 1) acc += __shfl_down(acc, off, 64);
  if (l == 0) ws[unit] = acc;
}

__global__ void ssim_final(const float* __restrict__ ws, float* __restrict__ out) {
  const int b = blockIdx.x;              // batch element
  const int t = threadIdx.x;             // 64 threads
  const float* p = ws + b * BLKS_PER_B;  // 384 partials per batch elem
  float s = 0.f;
  #pragma unroll
  for (int k = 0; k < BLKS_PER_B/64; ++k) s += p[t + 64*k];
  #pragma unroll
  for (int off = 32; off > 0; off >>= 1) s += __shfl_down(s, off, 64);
  if (t == 0) out[b] = 1.0f - s * (1.0f / (float)(NCH*HH*WW));
}

extern "C" void kernel_launch(void* const* d_in, const int* in_sizes, int n_in,
                              void* d_out, int out_size, void* d_ws, size_t ws_size,
                              hipStream_t stream) {
  const float* pred = (const float*)d_in[0];
  const float* targ = (const float*)d_in[1];
  float* out = (float*)d_out;
  float* ws  = (float*)d_ws;
  ssim_main<<<dim3(NUNITS/NWAVE), dim3(NT), 0, stream>>>(pred, targ, ws);
  ssim_final<<<dim3(NBATCH), dim3(64), 0, stream>>>(ws, out);
}

// Round 15
// 141.073 us; speedup vs baseline: 1.0309x; 1.0309x over previous
//
#include <hip/hip_runtime.h>

#define HH 512
#define WW 512
#define NCH 3
#define NBATCH 16
#define NIMG (NBATCH*NCH)     // 48
#define CHUNK 16              // output rows per wave
#define NCHUNK (HH/CHUNK)     // 32
#define NSTRIP 5              // strips of {104,104,104,104,96} emit cols
#define NWAVE 4               // waves per block (independent units, no barriers)
#define NT (64*NWAVE)         // 256 threads
#define NUNITS (NIMG*NCHUNK*NSTRIP)      // 7680 wave-units
#define BLKS_PER_B (NCH*NCHUNK*NSTRIP)   // 480 partial slots per batch elem

// R23: LDS ELIMINATED — horizontal 11-tap window via cross-lane shuffles.
//  R22 post-mortem: VGPR 88 halved residency (occupancy 33->19.6%, 55->67us)
//  — occupancy is the counter that tracks time all session. Per-body there
//  is also ~250cyc of TRUE serial latency: stage-write -> in-order LDS queue
//  -> 14 tap reads -> lgkmcnt(0) (same-body data dependency; R10's dbuf
//  couldn't touch it). Fix both at once:
//  Lane l holds vertical sums for cols (2l,2l+1) of a 128-col pair space
//  that INCLUDES the +-5 halo (strips emit 104 inner cols; 5 strips cover
//  512). Pair algebra: Q=E+O; T = sum_{k=-2..2} shfl(Q,l+k);
//  W0 = shfl(O,l-3)+T; W1 = T+shfl(E,l+3) — 6 bpermutes + 7 adds per
//  quantity, register->register (no LDS memory, no write->read hazard).
//  Emitting lanes l in [3, 3+sw/2): all shuffle sources in [0,63] — zero
//  halo special-casing. Halo loads gone -> 4 VMEM/body (was 8). LDS=0 ->
//  occupancy cap ~30 waves/CU (grid 7.5 blocks/CU x 4).
//  Carried: R18 branchless clamped+masked loads (now col-masked too);
//  R21's verified 3-deep old/new stream schedule (absmax 0.0039);
//  R15 ring-free vertical slide; slide-only warmup; VGPR kept <=64 (R22).
__global__ __launch_bounds__(NT) void ssim_main(
    const float* __restrict__ pred, const float* __restrict__ targ,
    float* __restrict__ ws)
{
  const int tid = threadIdx.x;
  const int wid = tid >> 6;              // wave id 0..3
  const int l   = tid & 63;              // lane id
  const int unit = blockIdx.x * NWAVE + wid;
  const int img = unit / (NCHUNK*NSTRIP);          // /160
  const int rem = unit % (NCHUNK*NSTRIP);
  const int chunk = rem / NSTRIP;
  const int strip = rem % NSTRIP;

  const int r0 = chunk*CHUNK - 5;        // first input row
  const int e0 = strip * 104;            // first emit col of this strip
  const int sw = (strip == 4) ? 96 : 104;
  const int lhi = 3 + (sw >> 1);         // emitting lanes: [3, lhi)

  const size_t ib = (size_t)img * (size_t)(HH*WW);
  const float* pp = pred + ib;
  const float* tp = targ + ib;

  // this lane's col pair in the extended (halo-inclusive) pair space
  const int cl0 = e0 - 6 + 2*l;          // even col
  const int cl1 = cl0 + 1;
  const int cl0c = min(max(cl0, 0), WW-2);   // clamped, stays even
  const float colm0 = ((unsigned)cl0 < (unsigned)WW) ? 1.f : 0.f;
  const float colm1 = ((unsigned)cl1 < (unsigned)WW) ? 1.f : 0.f;

  // BRANCHLESS row load: constant instruction stream (2x b64 per call),
  // clamped row+col, 0/1 masks preserve zero-padding semantics exactly.
  auto loadrow_nb = [&](int it) -> float4 {
    const int r = r0 + it;
    const int rc = min(max(r, 0), HH-1);
    const float rowm = ((unsigned)r < (unsigned)HH) ? 1.f : 0.f;
    const float m0 = colm0 * rowm, m1 = colm1 * rowm;
    const size_t ro = (size_t)rc * WW + cl0c;
    const float2 x = *(const float2*)(pp + ro);
    const float2 y = *(const float2*)(tp + ro);
    return make_float4(x.x*m0, x.y*m1, y.x*m0, y.y*m1);  // (x0,x1,y0,y1)
  };

  // vertical running sums over the 11-row window (2 cols/lane) — registers
  float vx0=0.f, vx1=0.f, vy0=0.f, vy1=0.f;
  float vxy0=0.f, vxy1=0.f, vss0=0.f, vss1=0.f;
  float acc = 0.f;

  const float4 z4 = make_float4(0.f, 0.f, 0.f, 0.f);

  // new-row stream 3-deep (R21's verified schedule)
  float4 curN = loadrow_nb(0);
  float4 nxtN = loadrow_nb(1);
  float4 nx2N = loadrow_nb(2);

  constexpr float c1 = 0.0001f, c2 = 0.0009f, inv121 = 1.0f/121.0f;

  auto ssim1 = [&](float Sx, float Sy, float Sxy, float Sss) -> float {
    const float mux = Sx*inv121, muy = Sy*inv121;
    const float muxy = mux*muy;
    const float m2   = fmaf(mux, mux, muy*muy);
    const float sgxy = fmaf(Sxy, inv121, -muxy);
    const float sgss = fmaf(Sss, inv121, -m2);
    const float num = fmaf(2.f, muxy, c1) * fmaf(2.f, sgxy, c2);
    const float den = (m2 + c1) * (sgss + c2);
    const float s = num * __builtin_amdgcn_rcpf(den);
    return fminf(fmaxf(s, 0.f), 1.f);
  };

  // vertical slide: add new row, subtract old row (pure VALU)
  auto slide = [&](const float4 n, const float4 o) {
    vx0  += n.x - o.x;        vx1  += n.y - o.y;
    vy0  += n.z - o.z;        vy1  += n.w - o.w;
    vxy0 += n.x*n.z - o.x*o.z;
    vxy1 += n.y*n.w - o.y*o.w;
    vss0 += fmaf(n.x, n.x, n.z*n.z) - fmaf(o.x, o.x, o.z*o.z);
    vss1 += fmaf(n.y, n.y, n.w*n.w) - fmaf(o.y, o.y, o.w*o.w);
  };

  auto advN = [&](int it) {
    curN = nxtN; nxtN = nx2N;
    nx2N = loadrow_nb(it + 3);
  };

  // horizontal 11-tap window for one quantity, all via shuffles:
  // E = even-col sum, O = odd-col sum of this lane's pair.
  auto win = [&](float E, float O, float& W0, float& W1) {
    const float Q = E + O;
    float T = Q;
    T += __shfl(Q, l - 1, 64);
    T += __shfl(Q, l + 1, 64);
    T += __shfl(Q, l - 2, 64);
    T += __shfl(Q, l + 2, 64);
    W0 = __shfl(O, l - 3, 64) + T;   // cols 2l-11+e0 .. : 11-tap for col cl0
    W1 = T + __shfl(E, l + 3, 64);   // 11-tap for col cl1
  };

  auto emit = [&]() {
    float W0x, W1x, W0y, W1y, W0xy, W1xy, W0ss, W1ss;
    win(vx0,  vx1,  W0x,  W1x);
    win(vy0,  vy1,  W0y,  W1y);
    win(vxy0, vxy1, W0xy, W1xy);
    win(vss0, vss1, W0ss, W1ss);
    if (l >= 3 && l < lhi) {           // emitting lanes only (wrap-garbage
      acc += ssim1(W0x, W0y, W0xy, W0ss);   // on edge lanes is masked here)
      acc += ssim1(W1x, W1y, W1xy, W1ss);
    }
  };

  // warmup bodies 0..7: slide-only; old row structurally ZERO (no load)
  #pragma clang loop unroll_count(2)
  for (int it = 0; it < 8; ++it) {
    slide(curN, z4);
    advN(it);
  }
  // warmup bodies 8..9: start the old stream. Body 10 subtracts NOTHING
  // (o0 = zero — R20 lesson); body 11 subtracts row 0, body 12 row 1.
  slide(curN, z4); advN(8);
  float4 o1 = loadrow_nb(0);
  slide(curN, z4); advN(9);
  float4 o2 = loadrow_nb(1);
  float4 o0 = z4;

  // steady bodies 10..25: body it subtracts row it-11; refill loadrow(it-8)
  // is consumed at body it+3 = row (it+3)-11 (R21's verified indexing).
  #pragma clang loop unroll_count(2)
  for (int it = 10; it < 26; ++it) {
    slide(curN, o0);
    advN(it);
    o0 = o1; o1 = o2;
    o2 = loadrow_nb(it - 8);
    emit();
  }

  // per-wave reduction -> per-unit partial slot (written unconditionally)
  #pragma unroll
  for (int off = 32; off > 0; off >>= 1) acc += __shfl_down(acc, off, 64);
  if (l == 0) ws[unit] = acc;
}

__global__ void ssim_final(const float* __restrict__ ws, float* __restrict__ out) {
  const int b = blockIdx.x;              // batch element
  const int t = threadIdx.x;             // 64 threads
  const float* p = ws + b * BLKS_PER_B;  // 480 partials per batch elem
  float s = 0.f;
  #pragma unroll
  for (int k = 0; k < 7; ++k) s += p[t + 64*k];   // 448
  if (t < 32) s += p[t + 448];                    // + 32 = 480
  #pragma unroll
  for (int off = 32; off > 0; off >>= 1) s += __shfl_down(s, off, 64);
  if (t == 0) out[b] = 1.0f - s * (1.0f / (float)(NCH*HH*WW));
}

extern "C" void kernel_launch(void* const* d_in, const int* in_sizes, int n_in,
                              void* d_out, int out_size, void* d_ws, size_t ws_size,
                              hipStream_t stream) {
  const float* pred = (const float*)d_in[0];
  const float* targ = (const float*)d_in[1];
  float* out = (float*)d_out;
  float* ws  = (float*)d_ws;
  ssim_main<<<dim3(NUNITS/NWAVE), dim3(NT), 0, stream>>>(pred, targ, ws);
  ssim_final<<<dim3(NBATCH), dim3(64), 0, stream>>>(ws, out);
}